// Round 1
// baseline (246.146 us; speedup 1.0000x reference)
//
#include <hip/hip_runtime.h>
#include <hip/hip_bf16.h>
#include <stdint.h>

using bf16 = __hip_bfloat16;
typedef __attribute__((ext_vector_type(8))) short bf16x8;   // 8 bf16 raw bits (4 VGPRs)
typedef __attribute__((ext_vector_type(4))) float f32x4;

__device__ __forceinline__ void async_load16(const void* g, void* l) {
    // global -> LDS direct copy, 16B per lane; LDS dest = wave-uniform base + lane*16
    __builtin_amdgcn_global_load_lds(
        (__attribute__((address_space(1))) const void*)g,
        (__attribute__((address_space(3))) void*)l,
        16, 0, 0);
}

__global__ __launch_bounds__(256) void cvt_f32_bf16(const float* __restrict__ src,
                                                    bf16* __restrict__ dst, int n) {
    int i = (blockIdx.x * 256 + threadIdx.x) * 8;
    if (i + 8 > n) return;
    float4 f0 = *(const float4*)(src + i);
    float4 f1 = *(const float4*)(src + i + 4);
    union { bf16 h[8]; uint4 u; } o;
    o.h[0] = __float2bfloat16(f0.x); o.h[1] = __float2bfloat16(f0.y);
    o.h[2] = __float2bfloat16(f0.z); o.h[3] = __float2bfloat16(f0.w);
    o.h[4] = __float2bfloat16(f1.x); o.h[5] = __float2bfloat16(f1.y);
    o.h[6] = __float2bfloat16(f1.z); o.h[7] = __float2bfloat16(f1.w);
    *(uint4*)(dst + i) = o.u;
}

// C[M x N] = A[M x K] * B[N x K]^T, A/B bf16 row-major (K contiguous).
// EPI==0: store C as bf16 into Cb. EPI==1: Cf[idx] = Res[idx] + (*scale_ptr)*acc (fp32).
// Tile: 128x128, BK=32, 256 threads = 4 waves in 2x2, each wave 64x64 via 4x4 MFMA 16x16x32.
template<int EPI>
__global__ __launch_bounds__(256) void gemm_nt(
    const bf16* __restrict__ A, const bf16* __restrict__ B,
    bf16* __restrict__ Cb, float* __restrict__ Cf,
    const float* __restrict__ Res, const float* __restrict__ scale_ptr,
    int M, int N, int K)
{
    __shared__ __align__(16) bf16 As[128 * 32];
    __shared__ __align__(16) bf16 Bs[128 * 32];

    const int tid  = threadIdx.x;
    const int wave = tid >> 6;
    const int lane = tid & 63;
    const int wm = wave >> 1, wn = wave & 1;
    const size_t bm = (size_t)blockIdx.x * 128;
    const size_t bn = (size_t)blockIdx.y * 128;

    f32x4 acc[4][4];
#pragma unroll
    for (int i = 0; i < 4; ++i)
#pragma unroll
        for (int j = 0; j < 4; ++j)
            acc[i][j] = (f32x4){0.f, 0.f, 0.f, 0.f};

    // staging: per global_load_lds call, wave covers 16 rows x 32 cols (1024B);
    // lane's element offset within region = lane*8 -> row = lane>>2, col = (lane&3)*8
    const int srow = lane >> 2;
    const int scol = (lane & 3) * 8;

    for (int k0 = 0; k0 < K; k0 += 32) {
#pragma unroll
        for (int c = 0; c < 2; ++c) {
            const int rbase = c * 64 + wave * 16;          // wave-uniform
            async_load16(A + (bm + rbase + srow) * (size_t)K + k0 + scol, &As[rbase * 32]);
            async_load16(B + (bn + rbase + srow) * (size_t)K + k0 + scol, &Bs[rbase * 32]);
        }
        __syncthreads();   // compiler drains vmcnt(0) before s_barrier

        bf16x8 af[4], bfr[4];
#pragma unroll
        for (int i = 0; i < 4; ++i)
            af[i] = *(const bf16x8*)&As[(wm * 64 + i * 16 + (lane & 15)) * 32 + (lane >> 4) * 8];
#pragma unroll
        for (int j = 0; j < 4; ++j)
            bfr[j] = *(const bf16x8*)&Bs[(wn * 64 + j * 16 + (lane & 15)) * 32 + (lane >> 4) * 8];
#pragma unroll
        for (int i = 0; i < 4; ++i)
#pragma unroll
            for (int j = 0; j < 4; ++j)
                acc[i][j] = __builtin_amdgcn_mfma_f32_16x16x32_bf16(af[i], bfr[j], acc[i][j], 0, 0, 0);
        __syncthreads();
    }

    // C/D layout (measured m89/m91): col = lane&15, row = (lane>>4)*4 + reg
    const int col_l = lane & 15;
    const int row_l = (lane >> 4) * 4;
    if (EPI == 0) {
#pragma unroll
        for (int i = 0; i < 4; ++i)
#pragma unroll
            for (int j = 0; j < 4; ++j)
#pragma unroll
                for (int r = 0; r < 4; ++r) {
                    size_t row = bm + wm * 64 + i * 16 + row_l + r;
                    size_t col = bn + wn * 64 + j * 16 + col_l;
                    Cb[row * (size_t)N + col] = __float2bfloat16(acc[i][j][r]);
                }
    } else {
        const float s = *scale_ptr;
#pragma unroll
        for (int i = 0; i < 4; ++i)
#pragma unroll
            for (int j = 0; j < 4; ++j)
#pragma unroll
                for (int r = 0; r < 4; ++r) {
                    size_t row = bm + wm * 64 + i * 16 + row_l + r;
                    size_t col = bn + wn * 64 + j * 16 + col_l;
                    size_t idx = row * (size_t)N + col;
                    Cf[idx] = Res[idx] + s * acc[i][j][r];
                }
    }
}

extern "C" void kernel_launch(void* const* d_in, const int* in_sizes, int n_in,
                              void* d_out, int out_size, void* d_ws, size_t ws_size,
                              hipStream_t stream) {
    // setup_inputs() order: hidden_states, w_down, w_up, w1, w2, residual_scale
    const float* hs     = (const float*)d_in[0];   // [8192, 2048] (flattened b,s)
    const float* w_down = (const float*)d_in[1];   // [512, 2048]
    const float* w_up   = (const float*)d_in[2];   // [2048, 512]
    const float* w1     = (const float*)d_in[3];   // [512, 512]
    const float* w2     = (const float*)d_in[4];   // [512, 512]
    const float* rs     = (const float*)d_in[5];   // scalar on device

    const int T = 8192, Q = 2048, H = 512;

    char* ws = (char*)d_ws;
    bf16* hs_b = (bf16*)(ws + 0);         // T*Q*2 = 33,554,432
    bf16* x_b  = (bf16*)(ws + 33554432);  // T*H*2 =  8,388,608
    bf16* h_b  = (bf16*)(ws + 41943040);
    bf16* o_b  = (bf16*)(ws + 50331648);
    bf16* wd_b = (bf16*)(ws + 58720256);  // H*Q*2 =  2,097,152
    bf16* w1_b = (bf16*)(ws + 60817408);  // H*H*2 =    524,288
    bf16* w2_b = (bf16*)(ws + 61341696);
    bf16* wu_b = (bf16*)(ws + 61865984);  // Q*H*2 =  2,097,152  (end: 63,963,136)

    // fp32 -> bf16 conversions (8 elems/thread)
    cvt_f32_bf16<<<dim3((T * Q) / 2048), dim3(256), 0, stream>>>(hs, hs_b, T * Q);
    cvt_f32_bf16<<<dim3((H * Q) / 2048), dim3(256), 0, stream>>>(w_down, wd_b, H * Q);
    cvt_f32_bf16<<<dim3((H * H) / 2048), dim3(256), 0, stream>>>(w1, w1_b, H * H);
    cvt_f32_bf16<<<dim3((H * H) / 2048), dim3(256), 0, stream>>>(w2, w2_b, H * H);
    cvt_f32_bf16<<<dim3((Q * H) / 2048), dim3(256), 0, stream>>>(w_up, wu_b, Q * H);

    dim3 blk(256);
    // x = hs @ w_down^T : M=8192, N=512, K=2048
    gemm_nt<0><<<dim3(T / 128, H / 128), blk, 0, stream>>>(hs_b, wd_b, x_b, nullptr, nullptr, nullptr, T, H, Q);
    // h = x @ w1^T : M=8192, N=512, K=512
    gemm_nt<0><<<dim3(T / 128, H / 128), blk, 0, stream>>>(x_b, w1_b, h_b, nullptr, nullptr, nullptr, T, H, H);
    // o = h @ w2^T : M=8192, N=512, K=512
    gemm_nt<0><<<dim3(T / 128, H / 128), blk, 0, stream>>>(h_b, w2_b, o_b, nullptr, nullptr, nullptr, T, H, H);
    // out = res + s * (o @ w_up^T) : M=8192, N=2048, K=512
    gemm_nt<1><<<dim3(T / 128, Q / 128), blk, 0, stream>>>(o_b, wu_b, nullptr, (float*)d_out, hs, rs, T, Q, H);
}